// Round 1
// baseline (383.079 us; speedup 1.0000x reference)
//
#include <hip/hip_runtime.h>

// Fused 3-stage strided conv1d encoder, 4 outputs per thread.
// x: [B,1,16384] fp32, three convs K=6 stride=2 VALID:
//   L1 = 8190, L2 = 4093, L3 = 2044.
// Thread tg computes out[row, 4*tg .. 4*tg+3] from x[row, 32*tg .. 32*tg+59]
//   (60 floats = 15 aligned float4; window halo amortized over 4 outputs).
// Per thread: 15 float4 loads, 28 c1 + 12 c2 + 4 out = 264 FMA, 1 float4 store.
// vs previous (1 output/thread): 9 loads + 138 FMA per OUTPUT.
// Memory floor: 268 MB read + 33.5 MB write => ~48 us at 6.3 TB/s.

#define L_IN  16384
#define L3    2044
#define KW    6
#define OPT   4      // outputs per thread (L3 = 2044 = 511 * 4 exactly)

__global__ __launch_bounds__(256) void encoder_fused_kernel(
    const float* __restrict__ x,
    const float* __restrict__ w1, const float* __restrict__ b1,
    const float* __restrict__ w2, const float* __restrict__ b2,
    const float* __restrict__ w3, const float* __restrict__ b3,
    float* __restrict__ out)
{
    const int tg  = blockIdx.x * blockDim.x + threadIdx.x;  // output-quad index
    const int j3  = OPT * tg;                               // first output index
    const int row = blockIdx.y;
    if (j3 >= L3) return;

    // Uniform weights (wave-uniform addresses -> cached loads)
    float W1[KW], W2[KW], W3[KW];
#pragma unroll
    for (int t = 0; t < KW; ++t) { W1[t] = w1[t]; W2[t] = w2[t]; W3[t] = w3[t]; }
    const float B1 = b1[0], B2 = b2[0], B3 = b3[0];

    // 60-float window = 15 aligned float4 (byte offset row*65536 + 128*tg)
    const float* xr = x + (size_t)row * L_IN + 8 * (size_t)j3;
    const float4* xv = reinterpret_cast<const float4*>(xr);
    float v[60];
#pragma unroll
    for (int i = 0; i < 15; ++i) {
        float4 t = xv[i];
        v[4 * i + 0] = t.x;
        v[4 * i + 1] = t.y;
        v[4 * i + 2] = t.z;
        v[4 * i + 3] = t.w;
    }

    // conv1: 28 intermediate outputs (relative), stride 2 over v
    float c1[28];
#pragma unroll
    for (int i = 0; i < 28; ++i) {
        float s = B1;
#pragma unroll
        for (int t = 0; t < KW; ++t) s = fmaf(W1[t], v[2 * i + t], s);
        c1[i] = s;
    }

    // conv2: 12 intermediate outputs, stride 2 over c1
    float c2[12];
#pragma unroll
    for (int i = 0; i < 12; ++i) {
        float s = B2;
#pragma unroll
        for (int t = 0; t < KW; ++t) s = fmaf(W2[t], c1[2 * i + t], s);
        c2[i] = s;
    }

    // conv3: 4 final outputs, stride 2 over c2 -> one aligned float4 store
    float o[OPT];
#pragma unroll
    for (int m = 0; m < OPT; ++m) {
        float s = B3;
#pragma unroll
        for (int t = 0; t < KW; ++t) s = fmaf(W3[t], c2[2 * m + t], s);
        o[m] = s;
    }
    float4 ov = make_float4(o[0], o[1], o[2], o[3]);
    // out row stride = 2044 floats = 8176 B = 511*16 -> float4 stores stay aligned
    *reinterpret_cast<float4*>(out + (size_t)row * L3 + j3) = ov;
}

extern "C" void kernel_launch(void* const* d_in, const int* in_sizes, int n_in,
                              void* d_out, int out_size, void* d_ws, size_t ws_size,
                              hipStream_t stream) {
    const float* x  = (const float*)d_in[0];
    const float* w1 = (const float*)d_in[1];
    const float* b1 = (const float*)d_in[2];
    const float* w2 = (const float*)d_in[3];
    const float* b2 = (const float*)d_in[4];
    const float* w3 = (const float*)d_in[5];
    const float* b3 = (const float*)d_in[6];
    float* out = (float*)d_out;

    const int B = in_sizes[0] / L_IN;  // 4096

    dim3 block(256);
    dim3 grid((L3 / OPT + 255) / 256, B);  // (2, 4096)
    encoder_fused_kernel<<<grid, block, 0, stream>>>(x, w1, b1, w2, b2, w3, b3, out);
}